// Round 2
// baseline (603.559 us; speedup 1.0000x reference)
//
#include <hip/hip_runtime.h>

// EdgeDecoder: out[b,i,j] = dot(z[b,i,:], w[:H]) + dot(z[b,j,:], w[H:]) + bias
// B=8, N=4096, H=256. ALL tensors fp32 per the reference file.
// Factorized: two thin matvecs (staged in d_ws) + broadcast outer add.
// Memory-bound on the 512 MiB fp32 output store (~87 us at 6.3 TB/s).

#define Bc 8
#define Nc 4096
#define Hc 256

// Kernel 1: per-row dual dot products.
// One wave (64 lanes) per row r in [0, B*N): each lane loads 4 floats of z
// and 4 of each w-half, dual dot, 64-lane shuffle reduce, lane 0 writes fp32.
__global__ __launch_bounds__(256) void ed_dots(
    const float* __restrict__ z,
    const float* __restrict__ w,
    const float* __restrict__ bias,
    float* __restrict__ rowc,
    float* __restrict__ colc)
{
    const int wid  = threadIdx.x >> 6;
    const int lane = threadIdx.x & 63;
    const int r = blockIdx.x * 4 + wid;          // row in [0, B*N)

    const float4 zv = *(const float4*)(z + (size_t)r * Hc + lane * 4);
    const float4 av = *(const float4*)(w + lane * 4);        // w[:H] slice
    const float4 bv = *(const float4*)(w + Hc + lane * 4);   // w[H:] slice

    float s1 = zv.x * av.x + zv.y * av.y + zv.z * av.z + zv.w * av.w;
    float s2 = zv.x * bv.x + zv.y * bv.y + zv.z * bv.z + zv.w * bv.w;

    #pragma unroll
    for (int off = 32; off > 0; off >>= 1) {
        s1 += __shfl_down(s1, off, 64);
        s2 += __shfl_down(s2, off, 64);
    }
    if (lane == 0) {
        rowc[r] = s1;
        colc[r] = s2 + bias[0];   // fold bias into the column term
    }
}

// Kernel 2: out[b,i,j] = rowc[b,i] + colc[b,j].
// One block per output row (b,i); thread t covers j = 16t..16t+15 (4 float4
// stores, 64 B/thread). colc slice (16 KB/batch) stays L2-hot across rows.
__global__ __launch_bounds__(256) void ed_outer(
    const float* __restrict__ rowc,
    const float* __restrict__ colc,
    float* __restrict__ out)
{
    const int bi = blockIdx.x;                 // (b*N + i) in [0, B*N)
    const float r = rowc[bi];
    const int cbase = bi & ~(Nc - 1);          // b*N
    const int j0 = threadIdx.x * 16;

    const float4* cp = (const float4*)(colc + cbase + j0);
    float4 c0 = cp[0], c1 = cp[1], c2 = cp[2], c3 = cp[3];

    c0.x += r; c0.y += r; c0.z += r; c0.w += r;
    c1.x += r; c1.y += r; c1.z += r; c1.w += r;
    c2.x += r; c2.y += r; c2.z += r; c2.w += r;
    c3.x += r; c3.y += r; c3.z += r; c3.w += r;

    float4* o = (float4*)(out + (size_t)bi * Nc + j0);
    o[0] = c0;
    o[1] = c1;
    o[2] = c2;
    o[3] = c3;
}

extern "C" void kernel_launch(void* const* d_in, const int* in_sizes, int n_in,
                              void* d_out, int out_size, void* d_ws, size_t ws_size,
                              hipStream_t stream) {
    const float* z    = (const float*)d_in[0];   // [B,N,H] fp32
    const float* w    = (const float*)d_in[1];   // [2H] fp32
    const float* bias = (const float*)d_in[2];   // [1] fp32
    float* out = (float*)d_out;                  // [B,N,N] fp32

    float* rowc = (float*)d_ws;           // B*N fp32
    float* colc = rowc + Bc * Nc;         // B*N fp32 (bias folded in)

    ed_dots<<<Bc * Nc / 4, 256, 0, stream>>>(z, w, bias, rowc, colc);
    ed_outer<<<Bc * Nc, 256, 0, stream>>>(rowc, colc, out);
}